// Round 12
// baseline (108.712 us; speedup 1.0000x reference)
//
#include <hip/hip_runtime.h>

#define N_NODES 50000
#define N_EDGES 1600000
#define IN_F 128
#define OUT_F 128   // HEADS*HEAD_DIM
#define HEADS 4
#define HEAD_DIM 32
#define NEG_SLOPE 0.2f

#define NB 391        // coarse buckets: bucket = dst >> 7 (128 nodes each)
#define CAP 4800      // per-bucket capacity (mean 4092, +11 sigma)
#define P1_EPT 16     // phase-1 edges per thread
#define P1_EPB (P1_EPT * 256)
#define GEMM_BLOCKS ((N_NODES + 63) / 64)            // 782
#define PART_BLOCKS ((N_EDGES + P1_EPB - 1) / P1_EPB) // 391

typedef __attribute__((ext_vector_type(8))) short short8v;
typedef __attribute__((ext_vector_type(4))) float f32x4;

__device__ __forceinline__ unsigned short f2bf(float f) {
    unsigned u = __builtin_bit_cast(unsigned, f);
    u += 0x7FFFu + ((u >> 16) & 1u);   // round-to-nearest-even
    return (unsigned short)(u >> 16);
}
__device__ __forceinline__ float bf_lo(unsigned v) {
    return __builtin_bit_cast(float, v << 16);
}
__device__ __forceinline__ float bf_hi(unsigned v) {
    return __builtin_bit_cast(float, v & 0xFFFF0000u);
}

// ---------------------------------------------------------------------------
// Prep: W fp32 -> bf16 + init bucket cursors (must precede the fused kernel).
// ---------------------------------------------------------------------------
__global__ __launch_bounds__(256) void prep_kernel(
    const float* __restrict__ W, unsigned short* __restrict__ wbf,
    int* __restrict__ gcursor)
{
    int t = blockIdx.x * 256 + threadIdx.x;
    if (t < 16384) wbf[t] = f2bf(W[t]);
    if (t < NB) gcursor[t] = t * CAP;
}

// ---------------------------------------------------------------------------
// Fused kernel: blocks [0, GEMM_BLOCKS) run the MFMA gemm+alpha path;
// blocks [GEMM_BLOCKS, +PART_BLOCKS) run the edge-partition path.
// ---------------------------------------------------------------------------
__global__ __launch_bounds__(256) void fused_gp_kernel(
    const float* __restrict__ x, const unsigned short* __restrict__ wbf,
    const float* __restrict__ a,
    unsigned short* __restrict__ hb,
    float* __restrict__ alpha_s, float* __restrict__ alpha_d,
    const int* __restrict__ ei, int* __restrict__ gcursor,
    unsigned* __restrict__ part)
{
    __shared__ int cnt[NB];
    __shared__ int gbase[NB];

    const int tid = threadIdx.x;

    if (blockIdx.x < GEMM_BLOCKS) {
        // ---------------- GEMM + alpha path ----------------
        const int wave = tid >> 6;
        const int lane = tid & 63;
        const int lr = lane & 15;
        const int lg = lane >> 4;
        const int nodeA = blockIdx.x * 64 + wave * 16 + lr;
        const int nrow = nodeA < N_NODES ? nodeA : 0;

        f32x4 acc[8];
        #pragma unroll
        for (int i = 0; i < 8; ++i) acc[i] = (f32x4){0.f, 0.f, 0.f, 0.f};

        #pragma unroll
        for (int ks = 0; ks < 4; ++ks) {
            const float* xp = x + (size_t)nrow * 128 + ks * 32 + lg * 8;
            float4 xa = *(const float4*)xp;
            float4 xc = *(const float4*)(xp + 4);
            short8v afrag;
            afrag[0] = (short)f2bf(xa.x); afrag[1] = (short)f2bf(xa.y);
            afrag[2] = (short)f2bf(xa.z); afrag[3] = (short)f2bf(xa.w);
            afrag[4] = (short)f2bf(xc.x); afrag[5] = (short)f2bf(xc.y);
            afrag[6] = (short)f2bf(xc.z); afrag[7] = (short)f2bf(xc.w);
            #pragma unroll
            for (int nf = 0; nf < 8; ++nf) {
                const short8v bfrag = *(const short8v*)(wbf + (size_t)(nf * 16 + lr) * 128 + ks * 32 + lg * 8);
                acc[nf] = __builtin_amdgcn_mfma_f32_16x16x32_bf16(afrag, bfrag, acc[nf], 0, 0, 0);
            }
        }

        float as_c[8], ad_c[8];
        #pragma unroll
        for (int nf = 0; nf < 8; ++nf) {
            const int idx = (nf >> 1) * 64 + (nf & 1) * 16 + lr;
            as_c[nf] = a[idx];
            ad_c[nf] = a[idx + 32];
        }

        const int nbase = blockIdx.x * 64 + wave * 16 + lg * 4;
        #pragma unroll
        for (int reg = 0; reg < 4; ++reg) {
            const int n2 = nbase + reg;
            if (n2 < N_NODES) {
                unsigned short* hp = hb + (size_t)n2 * 128 + lr;
                #pragma unroll
                for (int nf = 0; nf < 8; ++nf)
                    hp[nf * 16] = f2bf(acc[nf][reg]);
            }
            float sh[4], th[4];
            #pragma unroll
            for (int hd = 0; hd < 4; ++hd) {
                sh[hd] = acc[2 * hd][reg] * as_c[2 * hd] + acc[2 * hd + 1][reg] * as_c[2 * hd + 1];
                th[hd] = acc[2 * hd][reg] * ad_c[2 * hd] + acc[2 * hd + 1][reg] * ad_c[2 * hd + 1];
            }
            #pragma unroll
            for (int off = 8; off >= 1; off >>= 1) {
                #pragma unroll
                for (int hd = 0; hd < 4; ++hd) {
                    sh[hd] += __shfl_xor(sh[hd], off);
                    th[hd] += __shfl_xor(th[hd], off);
                }
            }
            if (lr == 0 && n2 < N_NODES) {
                #pragma unroll
                for (int hd = 0; hd < 4; ++hd) {
                    alpha_s[n2 * 4 + hd] = sh[hd];
                    alpha_d[n2 * 4 + hd] = th[hd];
                }
            }
        }
    } else {
        // ---------------- edge partition path ----------------
        const int e0 = (blockIdx.x - GEMM_BLOCKS) * P1_EPB;

        for (int i = tid; i < NB; i += 256) cnt[i] = 0;
        __syncthreads();

        unsigned pk[P1_EPT];
        int bk[P1_EPT];
        int loc[P1_EPT];
        #pragma unroll
        for (int c4 = 0; c4 < P1_EPT / 4; ++c4) {
            int e = e0 + c4 * 1024 + tid * 4;
            if (e < N_EDGES) {
                int4 s4 = *(const int4*)(ei + e);
                int4 d4 = *(const int4*)(ei + N_EDGES + e);
                int ss[4] = {s4.x, s4.y, s4.z, s4.w};
                int dd[4] = {d4.x, d4.y, d4.z, d4.w};
                #pragma unroll
                for (int j = 0; j < 4; ++j) {
                    int k = c4 * 4 + j;
                    int bb = dd[j] >> 7;
                    bk[k] = bb;
                    pk[k] = ((unsigned)(dd[j] & 127) << 16) | (unsigned)ss[j];
                    loc[k] = atomicAdd(&cnt[bb], 1);
                }
            } else {
                #pragma unroll
                for (int j = 0; j < 4; ++j) bk[c4 * 4 + j] = -1;
            }
        }
        __syncthreads();
        for (int bq = tid; bq < NB; bq += 256)
            gbase[bq] = atomicAdd(&gcursor[bq], cnt[bq]);
        __syncthreads();
        #pragma unroll
        for (int k = 0; k < P1_EPT; ++k)
            if (bk[k] >= 0)
                part[gbase[bk[k]] + loc[k]] = pk[k];
    }
}

// ---------------------------------------------------------------------------
// Phase 2: one block per bucket (391 blocks, 128 nodes each). Per-wave
// histograms + cursors cut LDS-atomic contention 4x.
// ---------------------------------------------------------------------------
__global__ __launch_bounds__(256) void bucket_kernel(
    const int* __restrict__ gcursor, const unsigned* __restrict__ part,
    unsigned short* __restrict__ srcs16,
    int* __restrict__ node_start, int* __restrict__ node_cnt)
{
    __shared__ unsigned ent[CAP];
    __shared__ unsigned short srt[CAP];
    __shared__ int cnt4[4][128];
    __shared__ int sc[128];
    __shared__ int cur4[4][128];

    const int b = blockIdx.x;
    const int tid = threadIdx.x;
    const int w = tid >> 6;
    const int bstart = b * CAP;
    int n_b = gcursor[b] - bstart;
    if (n_b > CAP) n_b = CAP;

    if (tid < 128) {
        cnt4[0][tid] = 0; cnt4[1][tid] = 0; cnt4[2][tid] = 0; cnt4[3][tid] = 0;
    }
    __syncthreads();

    for (int i = tid; i < n_b; i += 256) {
        unsigned e = part[bstart + i];
        ent[i] = e;
        atomicAdd(&cnt4[w][e >> 16], 1);
    }
    __syncthreads();

    int c = 0;
    if (tid < 128) {
        c = cnt4[0][tid] + cnt4[1][tid] + cnt4[2][tid] + cnt4[3][tid];
        sc[tid] = c;
    }
    __syncthreads();
    #pragma unroll
    for (int off = 1; off < 128; off <<= 1) {
        int v = 0;
        if (tid < 128 && tid >= off) v = sc[tid - off];
        __syncthreads();
        if (tid < 128) sc[tid] += v;
        __syncthreads();
    }
    if (tid < 128) {
        int eb = sc[tid] - c;
        int c0 = cnt4[0][tid], c1 = cnt4[1][tid], c2 = cnt4[2][tid];
        cur4[0][tid] = eb;
        cur4[1][tid] = eb + c0;
        cur4[2][tid] = eb + c0 + c1;
        cur4[3][tid] = eb + c0 + c1 + c2;
        const int node = b * 128 + tid;
        if (node < N_NODES) {
            node_start[node] = bstart + eb;
            node_cnt[node] = c;
        }
    }
    __syncthreads();

    for (int i = tid; i < n_b; i += 256) {
        unsigned e = ent[i];
        int loc = atomicAdd(&cur4[w][e >> 16], 1);
        srt[loc] = (unsigned short)(e & 0xFFFFu);
    }
    __syncthreads();

    const unsigned* srt32 = (const unsigned*)srt;
    unsigned* dst32 = (unsigned*)(srcs16 + bstart);
    const int nw2 = (n_b + 1) >> 1;
    for (int i = tid; i < nw2; i += 256) dst32[i] = srt32[i];
}

// ---------------------------------------------------------------------------
// Gather: one wave per dst node, split into two 32-lane halves; each half
// handles one edge of a pair with dwordx2 h loads (lane q owns features
// 4q..4q+3). Per 2 edges: 1 srcs + 1 alpha + 1 h (dwordx2) VMEM. 8 pairs
// (16 edges) in flight per iteration; cross-half shfl_xor(32) reduce at end.
// ---------------------------------------------------------------------------
__global__ __launch_bounds__(256) void gather_kernel(
    const unsigned short* __restrict__ srcs,
    const int* __restrict__ node_start, const int* __restrict__ node_cnt,
    const unsigned* __restrict__ h32,
    const float* __restrict__ alpha_s, const float* __restrict__ alpha_d,
    float* __restrict__ out)
{
    const int wid = (blockIdx.x * 256 + threadIdx.x) >> 6;
    if (wid >= N_NODES) return;
    const int lane = threadIdx.x & 63;
    const int half = lane >> 5;          // which edge of each pair
    const int q = lane & 31;             // dword-pair index within the h row
    const int head = q >> 3;
    const int start = node_start[wid];
    const int cnt = node_cnt[wid];
    const float adv = alpha_d[wid * 4 + head];

    float acc0 = 0.f, acc1 = 0.f, acc2 = 0.f, acc3 = 0.f;

    int i = start;
    const int endp = start + (cnt & ~1);

    // 8-pair (16-edge) unrolled loop, staged for MLP
    for (; i + 16 <= endp; i += 16) {
        unsigned sv[8];
        #pragma unroll
        for (int k = 0; k < 8; ++k)
            sv[k] = srcs[i + 2 * k + half];
        uint2 hv[8];
        #pragma unroll
        for (int k = 0; k < 8; ++k)
            hv[k] = *(const uint2*)(h32 + ((size_t)sv[k] << 6) + (q << 1));
        float tv[8];
        #pragma unroll
        for (int k = 0; k < 8; ++k) {
            float t = alpha_s[(sv[k] << 2) + head] + adv;
            tv[k] = t > 0.f ? t : NEG_SLOPE * t;
        }
        #pragma unroll
        for (int k = 0; k < 8; ++k) {
            acc0 = fmaf(tv[k], bf_lo(hv[k].x), acc0);
            acc1 = fmaf(tv[k], bf_hi(hv[k].x), acc1);
            acc2 = fmaf(tv[k], bf_lo(hv[k].y), acc2);
            acc3 = fmaf(tv[k], bf_hi(hv[k].y), acc3);
        }
    }
    // pair tail
    for (; i < endp; i += 2) {
        unsigned s = srcs[i + half];
        float t = alpha_s[(s << 2) + head] + adv;
        t = t > 0.f ? t : NEG_SLOPE * t;
        uint2 v = *(const uint2*)(h32 + ((size_t)s << 6) + (q << 1));
        acc0 = fmaf(t, bf_lo(v.x), acc0);
        acc1 = fmaf(t, bf_hi(v.x), acc1);
        acc2 = fmaf(t, bf_lo(v.y), acc2);
        acc3 = fmaf(t, bf_hi(v.y), acc3);
    }
    // odd last edge: both halves load it, half 1 contributes zero
    if (cnt & 1) {
        unsigned s = srcs[endp];
        float t = alpha_s[(s << 2) + head] + adv;
        t = t > 0.f ? t : NEG_SLOPE * t;
        if (half) t = 0.f;
        uint2 v = *(const uint2*)(h32 + ((size_t)s << 6) + (q << 1));
        acc0 = fmaf(t, bf_lo(v.x), acc0);
        acc1 = fmaf(t, bf_hi(v.x), acc1);
        acc2 = fmaf(t, bf_lo(v.y), acc2);
        acc3 = fmaf(t, bf_hi(v.y), acc3);
    }

    acc0 += __shfl_xor(acc0, 32);
    acc1 += __shfl_xor(acc1, 32);
    acc2 += __shfl_xor(acc2, 32);
    acc3 += __shfl_xor(acc3, 32);
    if (half == 0) {
        float4 r = {acc0, acc1, acc2, acc3};
        *(float4*)(out + (size_t)wid * 128 + q * 4) = r;
    }
}

// ---------------------------------------------------------------------------
// Fallback atomic edge kernel (only if ws_size too small for the sort path).
// ---------------------------------------------------------------------------
__global__ __launch_bounds__(256) void edge_kernel(
    const int* __restrict__ ei,
    const unsigned* __restrict__ h32,
    const float* __restrict__ alpha_s, const float* __restrict__ alpha_d,
    float* __restrict__ out)
{
    const unsigned total = (unsigned)N_EDGES * 32u;
    const unsigned stride = gridDim.x * blockDim.x;
    for (unsigned i = blockIdx.x * blockDim.x + threadIdx.x; i < total; i += stride) {
        const int e = (int)(i >> 5);
        const int c = (int)(i & 31);
        const int src = ei[e];
        const int dst = ei[N_EDGES + e];
        const int head = c >> 3;

        float att = alpha_s[src * 4 + head] + alpha_d[dst * 4 + head];
        att = att > 0.f ? att : NEG_SLOPE * att;

        unsigned v0 = h32[(size_t)src * 64 + c * 2];
        unsigned v1 = h32[(size_t)src * 64 + c * 2 + 1];
        float* po = out + (size_t)dst * 128 + c * 4;
        atomicAdd(po + 0, att * bf_lo(v0));
        atomicAdd(po + 1, att * bf_hi(v0));
        atomicAdd(po + 2, att * bf_lo(v1));
        atomicAdd(po + 3, att * bf_hi(v1));
    }
}

extern "C" void kernel_launch(void* const* d_in, const int* in_sizes, int n_in,
                              void* d_out, int out_size, void* d_ws, size_t ws_size,
                              hipStream_t stream) {
    const float* x  = (const float*)d_in[0];
    const int*   ei = (const int*)d_in[1];
    const float* W  = (const float*)d_in[2];
    const float* a  = (const float*)d_in[3];
    float* out = (float*)d_out;

    // Workspace layout (~26 MB total):
    //   hb      12.8 MB | alpha_s/d 1.6 MB | part 7.5 MB | srcs16 3.75 MB |
    //   gcursor 512 i32 | node_start/cnt 0.4 MB | wbf 32 KB
    unsigned short* hb = (unsigned short*)d_ws;
    float* as = (float*)(hb + (size_t)N_NODES * 128);
    float* ad = as + (size_t)N_NODES * 4;
    unsigned* part = (unsigned*)(ad + (size_t)N_NODES * 4);
    unsigned short* srcs16 = (unsigned short*)(part + (size_t)NB * CAP);
    int* gcursor = (int*)(srcs16 + (size_t)NB * CAP);
    int* node_start = gcursor + 512;
    int* node_cnt   = node_start + 50176;
    unsigned short* wbf = (unsigned short*)(node_cnt + 50176);
    const size_t needed = (size_t)((char*)(wbf + 16384) - (char*)d_ws);

    prep_kernel<<<64, 256, 0, stream>>>(W, wbf, gcursor);

    if (ws_size >= needed) {
        fused_gp_kernel<<<GEMM_BLOCKS + PART_BLOCKS, 256, 0, stream>>>(
            x, wbf, a, hb, as, ad, ei, gcursor, part);
        bucket_kernel<<<NB, 256, 0, stream>>>(gcursor, part, srcs16, node_start, node_cnt);
        gather_kernel<<<(N_NODES * 64 + 255) / 256, 256, 0, stream>>>(
            srcs16, node_start, node_cnt, (const unsigned*)hb, as, ad, out);
    } else {
        fused_gp_kernel<<<GEMM_BLOCKS, 256, 0, stream>>>(
            x, wbf, a, hb, as, ad, ei, gcursor, part);
        hipMemsetAsync(d_out, 0, (size_t)out_size * sizeof(float), stream);
        edge_kernel<<<4096, 256, 0, stream>>>(ei, (const unsigned*)hb, as, ad, out);
    }
}